// Round 11
// baseline (92.639 us; speedup 1.0000x reference)
//
#include <hip/hip_runtime.h>
#include <cmath>

#define Bn 8
#define Tn 2048
#define Cn 1024
#define Kn 128

typedef __attribute__((ext_vector_type(8))) short short8;
typedef __attribute__((ext_vector_type(4))) float f32x4;
typedef unsigned short u16;
typedef unsigned int u32;

#define NEGINF (-__builtin_huge_valf())

__device__ __forceinline__ u16 f2b(float f) {
    u32 u = __float_as_uint(f);
    u32 r = (u + 0x7FFFu + ((u >> 16) & 1u)) >> 16;
    return (u16)r;
}
__device__ __forceinline__ float b2f(u16 v) {
    u32 u = ((u32)v) << 16;
    return __uint_as_float(u);
}
// packed fp32x2 -> bf16x2 (lo -> [15:0], hi -> [31:16]), RNE.
__device__ __forceinline__ u32 cvtpk(float lo, float hi) {
    u32 r;
    asm("v_cvt_pk_bf16_f32 %0, %1, %2" : "=v"(r) : "v"(lo), "v"(hi));
    return r;
}

__device__ __forceinline__ void load_lds16(const u16* g, u16* l) {
    __builtin_amdgcn_global_load_lds(
        (const __attribute__((address_space(1))) u32*)(g),
        (__attribute__((address_space(3))) u32*)(l), 16, 0, 0);
}

// ---------------------------------------------------------------------------
// prep: W [1024 c][128 n] fp32 -> W^T bf16 [3][128 n][1024 c]  (= [384][1024])
// ---------------------------------------------------------------------------
__global__ __launch_bounds__(256)
void prep_kernel(const float* __restrict__ Wq, const float* __restrict__ Wk,
                 const float* __restrict__ Wv, u16* __restrict__ Wt)
{
    int id = blockIdx.x * 256 + threadIdx.x;
    int w   = id >> 15;
    int rem = id & 32767;
    int c   = rem >> 5;
    int n4  = (rem & 31) << 2;
    const float* W = (w == 0) ? Wq : (w == 1) ? Wk : Wv;
    float4 v = *(const float4*)(W + (size_t)c * Kn + n4);
    u16* dst = Wt + (size_t)w * Kn * Cn;
    dst[(size_t)(n4 + 0) * Cn + c] = f2b(v.x);
    dst[(size_t)(n4 + 1) * Cn + c] = f2b(v.y);
    dst[(size_t)(n4 + 2) * Cn + c] = f2b(v.z);
    dst[(size_t)(n4 + 3) * Cn + c] = f2b(v.w);
}

// ---------------------------------------------------------------------------
// proj6: fused q|k|v GEMM -- x read ONCE. 64-row stripe x 384 cols per block,
// grid 256 (1/CU), 8 waves = 2 row-halves x 4 col-quarters (wave: 32x96).
// x: fp32->reg->cvtpk->LDS (16KB dbuf, 2-step lookahead). W: global->REG
// per wave (12 dwordx4/step from L2, dbuf, no barrier dep). Raw s_barrier
// drains lgkmcnt only; all VMEM stays in flight across it.
// ---------------------------------------------------------------------------
__global__ __launch_bounds__(512, 2)
void proj6_kernel(const float* __restrict__ x, const u16* __restrict__ Wt,
                  u16* __restrict__ qkv)
{
    const int rt   = blockIdx.x;                  // 0..255
    const int row0 = rt * 64;
    const int tid  = threadIdx.x;
    const int lane = tid & 63;
    const int wid  = tid >> 6;                    // 0..7
    const int l15  = lane & 15, lh = lane >> 4;
    const int wm0 = (wid >> 2) * 32;              // row-half
    const int wn0 = (wid & 3) * 96;               // col-quarter (global n)

    // x only: 2 x [64][64] bf16, swizzled. 16 KB.
    __shared__ u16 xs[8192];

    // per-ng W base pointers (lane-varying): row (wn0+ng*16+l15), col lh*8
    const u16* wb[6];
    #pragma unroll
    for (int ng = 0; ng < 6; ++ng)
        wb[ng] = Wt + (size_t)(wn0 + ng * 16 + l15) * Cn + lh * 8;

    auto loadW = [&](int kk, short8* wf) {
        #pragma unroll
        for (int kc = 0; kc < 2; ++kc)
            #pragma unroll
            for (int ng = 0; ng < 6; ++ng)
                wf[kc * 6 + ng] = *(const short8*)(wb[ng] + kk + kc * 32);
    };
    auto loadX = [&](int kk, float4* xr) {
        int r = tid >> 3, c8 = tid & 7;
        const float* s = x + (size_t)(row0 + r) * Cn + kk + c8 * 8;
        xr[0] = *(const float4*)(s);
        xr[1] = *(const float4*)(s + 4);
    };
    auto writeX = [&](int buf, const float4* xr) {
        int r = tid >> 3, c8 = tid & 7;
        uint4 pk;
        pk.x = cvtpk(xr[0].x, xr[0].y);
        pk.y = cvtpk(xr[0].z, xr[0].w);
        pk.z = cvtpk(xr[1].x, xr[1].y);
        pk.w = cvtpk(xr[1].z, xr[1].w);
        *(uint4*)(xs + buf * 4096 + r * 64 + ((c8 ^ (r & 7)) << 3)) = pk;
    };

    f32x4 acc[2][6];
    #pragma unroll
    for (int i = 0; i < 2; ++i)
        #pragma unroll
        for (int j = 0; j < 6; ++j) acc[i][j] = (f32x4){0.f, 0.f, 0.f, 0.f};

    auto compute = [&](int buf, const short8* wf) {
        const u16* Xb = xs + buf * 4096;
        #pragma unroll
        for (int kc = 0; kc < 2; ++kc) {
            short8 af[2];
            #pragma unroll
            for (int mg = 0; mg < 2; ++mg) {
                int row = wm0 + mg * 16 + l15;
                int ch  = (kc * 4 + lh) ^ (row & 7);
                af[mg] = *(const short8*)(Xb + row * 64 + ch * 8);
            }
            #pragma unroll
            for (int mg = 0; mg < 2; ++mg)
                #pragma unroll
                for (int ng = 0; ng < 6; ++ng)
                    acc[mg][ng] = __builtin_amdgcn_mfma_f32_16x16x32_bf16(
                        af[mg], wf[kc * 6 + ng], acc[mg][ng], 0, 0, 0);
        }
    };

    short8 wfA[12], wfB[12];
    float4 xA[2], xB[2];
    // prologue
    loadX(0, xA);            // x(0)
    loadW(0, wfA);           // W(0)
    loadX(64, xB);           // x(1)
    writeX(0, xA);           // implicit wait on xA; cvt; LDS buf0
    asm volatile("s_waitcnt lgkmcnt(0)" ::: "memory");
    __builtin_amdgcn_sched_barrier(0);
    __builtin_amdgcn_s_barrier();
    __builtin_amdgcn_sched_barrier(0);

    // steady: entering step t, LDS buf(t&1)=x(t); regs: xW=x(t+1), wfCur=W(t)
    auto step = [&](int t, float4* xW, float4* xL, short8* wfCur, short8* wfNext) {
        const int buf = t & 1;
        if (t + 2 < 16) loadX((t + 2) * 64, xL);
        if (t + 1 < 16) loadW((t + 1) * 64, wfNext);
        compute(buf, wfCur);
        if (t + 1 < 16) writeX(buf ^ 1, xW);
        if (t < 15) {
            asm volatile("s_waitcnt lgkmcnt(0)" ::: "memory");
            __builtin_amdgcn_sched_barrier(0);
            __builtin_amdgcn_s_barrier();
            __builtin_amdgcn_sched_barrier(0);
        }
    };

    for (int tt = 0; tt < 8; ++tt) {
        step(2 * tt,     xB, xA, wfA, wfB);
        step(2 * tt + 1, xA, xB, wfB, wfA);
    }

    // epilogue: n_glob -> (w, n_local)
    #pragma unroll
    for (int mg = 0; mg < 2; ++mg)
        #pragma unroll
        for (int ng = 0; ng < 6; ++ng) {
            int n_glob = wn0 + ng * 16 + l15;
            int w  = n_glob >> 7;
            int nl = n_glob & 127;
            u16* outp = qkv + (size_t)w * Bn * Tn * Kn;
            #pragma unroll
            for (int r = 0; r < 4; ++r) {
                int m = row0 + wm0 + mg * 16 + lh * 4 + r;
                outp[(size_t)m * Kn + nl] = f2b(acc[mg][ng][r]);
            }
        }
}

// ---------------------------------------------------------------------------
// attn: causal flash, split-s equal-work blocks (R8 version, setprio removed).
// ---------------------------------------------------------------------------
__device__ const int g_job_qi[32] = {0, 1,1, 2,2,2, 3,3,3,3, 4,4,4,4,
                                     5,5,5,5,5, 6,6,6,6,6,6, 7,7,7,7,7,7,7};
__device__ const int g_sup_b[32] = {0, 0,4, 0,4,8, 0,4,8,12, 0,5,10,15,
                                    0,4,9,14,19, 0,4,9,14,18,23, 0,4,9,13,18,22,27};
__device__ const int g_sup_e[32] = {4, 4,8, 4,8,12, 4,8,12,16, 5,10,15,20,
                                    4,9,14,19,24, 4,9,14,18,23,28, 4,9,13,18,22,27,32};

__global__ __launch_bounds__(512, 2)
void attn_kernel(const u16* __restrict__ qg_, const u16* __restrict__ kg_,
                 const u16* __restrict__ vg_, u16* __restrict__ pO,
                 float* __restrict__ pM, float* __restrict__ pL)
{
    const int b   = blockIdx.x;
    const int job = blockIdx.y;
    const int qi  = g_job_qi[job];
    const int sb  = g_sup_b[job], se = g_sup_e[job];

    const u16* qw = qg_ + (size_t)b * Tn * Kn;
    const u16* kw = kg_ + (size_t)b * Tn * Kn;
    const u16* vw = vg_ + (size_t)b * Tn * Kn;

    const int tid  = threadIdx.x;
    const int lane = tid & 63;
    const int wid  = tid >> 6;
    const int l15  = lane & 15, lh = lane >> 4;

    const int q0 = qi * 256 + wid * 32;
    const int qmax_w = q0 + 31;

    __shared__ u16 lds[32768];

    short8 qf[2][4];
    #pragma unroll
    for (int g = 0; g < 2; ++g)
        #pragma unroll
        for (int kc = 0; kc < 4; ++kc)
            qf[g][kc] = *(const short8*)(qw + (size_t)(q0 + g * 16 + l15) * Kn
                                         + kc * 32 + lh * 8);

    f32x4 acc[8][2];
    #pragma unroll
    for (int dt = 0; dt < 8; ++dt)
        #pragma unroll
        for (int g = 0; g < 2; ++g) acc[dt][g] = (f32x4){0.f, 0.f, 0.f, 0.f};
    float m_g[2] = {NEGINF, NEGINF}, l_g[2] = {0.f, 0.f};

    const float scale = 0.08838834764831843f;

    auto stageK = [&](int sup, int buf) {
        const u16* src = kw + (size_t)sup * 64 * Kn;
        u16* dst = lds + buf * 8192;
        #pragma unroll
        for (int i = 0; i < 2; ++i) {
            int u = wid * 128 + i * 64 + lane;
            int row = u >> 4;
            int c16 = (u & 15) ^ (row & 7);
            load_lds16(src + (size_t)row * Kn + c16 * 8,
                       dst + (size_t)(wid * 128 + i * 64) * 8);
        }
    };
    auto loadV = [&](int sup, uint4* vr) {
        const u16* src = vw + (size_t)sup * 64 * Kn;
        #pragma unroll
        for (int r = 0; r < 2; ++r) {
            int s  = tid & 63;
            int u8 = (tid >> 6) + 8 * r;
            vr[r] = *(const uint4*)(src + (size_t)s * Kn + u8 * 8);
        }
    };
    auto writeV = [&](int buf, const uint4* vr) {
        u16* dst = lds + 16384 + buf * 8192;
        #pragma unroll
        for (int r = 0; r < 2; ++r) {
            int s  = tid & 63;
            int u8 = (tid >> 6) + 8 * r;
            const u16* e = (const u16*)&vr[r];
            #pragma unroll
            for (int j = 0; j < 8; ++j) {
                int d = u8 * 8 + j;
                dst[d * 64 + (((s >> 3) ^ j) << 3) + (s & 7)] = e[j];
            }
        }
    };

    uint4 vreg[2];
    stageK(sb, 0);
    loadV(sb, vreg);
    writeV(0, vreg);

    for (int sup = sb; sup < se; ++sup) {
        const int cur = (sup - sb) & 1;
        __syncthreads();
        const bool have_next = (sup + 1 < se);
        if (have_next) {
            stageK(sup + 1, cur ^ 1);
            loadV(sup + 1, vreg);
        }
        if (sup * 64 <= qmax_w) {
            const u16* Kb = lds + cur * 8192;
            const u16* Vb = lds + 16384 + cur * 8192;
            f32x4 sf[4][2];
            #pragma unroll
            for (int mt = 0; mt < 4; ++mt)
                #pragma unroll
                for (int g = 0; g < 2; ++g) sf[mt][g] = (f32x4){0.f,0.f,0.f,0.f};
            #pragma unroll
            for (int kc = 0; kc < 4; ++kc) {
                short8 a[4];
                #pragma unroll
                for (int mt = 0; mt < 4; ++mt) {
                    int row = mt * 16 + l15;
                    int ch  = (kc * 4 + lh) ^ (row & 7);
                    a[mt] = *(const short8*)(Kb + row * 128 + ch * 8);
                }
                #pragma unroll
                for (int mt = 0; mt < 4; ++mt)
                    #pragma unroll
                    for (int g = 0; g < 2; ++g)
                        sf[mt][g] = __builtin_amdgcn_mfma_f32_16x16x32_bf16(
                            a[mt], qf[g][kc], sf[mt][g], 0, 0, 0);
            }
            const int sbase = sup * 64;
            u32 upk[2][4][2];
            float alpha_g[2];
            #pragma unroll
            for (int g = 0; g < 2; ++g) {
                const int qg = q0 + g * 16 + l15;
                float pv[16];
                float pm = NEGINF;
                #pragma unroll
                for (int mt = 0; mt < 4; ++mt)
                    #pragma unroll
                    for (int r = 0; r < 4; ++r) {
                        int sg = sbase + mt * 16 + lh * 4 + r;
                        float vv = sf[mt][g][r] * scale;
                        vv = (sg > qg) ? NEGINF : vv;
                        pv[mt * 4 + r] = vv;
                        pm = fmaxf(pm, vv);
                    }
                pm = fmaxf(pm, __shfl_xor(pm, 16));
                pm = fmaxf(pm, __shfl_xor(pm, 32));
                float mn  = fmaxf(m_g[g], pm);
                float mns = (mn == NEGINF) ? 0.f : mn;
                float al  = __expf(m_g[g] - mns);
                m_g[g] = mn;
                alpha_g[g] = al;
                float ps = 0.f;
                #pragma unroll
                for (int i = 0; i < 16; ++i) { pv[i] = __expf(pv[i] - mns); ps += pv[i]; }
                ps += __shfl_xor(ps, 16);
                ps += __shfl_xor(ps, 32);
                l_g[g] = l_g[g] * al + ps;
                #pragma unroll
                for (int mt = 0; mt < 4; ++mt)
                    #pragma unroll
                    for (int h = 0; h < 2; ++h)
                        upk[g][mt][h] = (u32)f2b(pv[mt * 4 + 2 * h])
                                      | ((u32)f2b(pv[mt * 4 + 2 * h + 1]) << 16);
            }
            #pragma unroll
            for (int dt = 0; dt < 8; ++dt)
                #pragma unroll
                for (int g = 0; g < 2; ++g)
                    acc[dt][g] *= alpha_g[g];
            #pragma unroll
            for (int ks = 0; ks < 2; ++ks) {
                short8 pf[2];
                #pragma unroll
                for (int g = 0; g < 2; ++g) {
                    union { u32 w[4]; short8 v; } uu;
                    #pragma unroll
                    for (int hp = 0; hp < 4; ++hp) {
                        int srcLane = l15 + 16 * ((lh & 1) * 2 + (hp >> 1));
                        u32 vA = __shfl(upk[g][2 * ks][hp & 1], srcLane, 64);
                        u32 vB = __shfl(upk[g][2 * ks + 1][hp & 1], srcLane, 64);
                        uu.w[hp] = (lh < 2) ? vA : vB;
                    }
                    pf[g] = uu.v;
                }
                #pragma unroll
                for (int dt = 0; dt < 8; ++dt) {
                    int d  = dt * 16 + l15;
                    int ch = (ks * 4 + lh) ^ (d & 7);
                    short8 av = *(const short8*)(Vb + d * 64 + ch * 8);
                    #pragma unroll
                    for (int g = 0; g < 2; ++g)
                        acc[dt][g] = __builtin_amdgcn_mfma_f32_16x16x32_bf16(
                            av, pf[g], acc[dt][g], 0, 0, 0);
                }
            }
        }
        if (have_next) writeV(cur ^ 1, vreg);
    }

    const size_t slotrow = ((size_t)b * 32 + job) * 256 + wid * 32;
    #pragma unroll
    for (int g = 0; g < 2; ++g) {
        size_t row = slotrow + g * 16 + l15;
        #pragma unroll
        for (int dt = 0; dt < 8; ++dt) {
            ushort4 o = { f2b(acc[dt][g][0]), f2b(acc[dt][g][1]),
                          f2b(acc[dt][g][2]), f2b(acc[dt][g][3]) };
            *(ushort4*)(pO + row * 128 + dt * 16 + lh * 4) = o;
        }
        if (lh == 0) {
            pM[row] = m_g[g];
            pL[row] = l_g[g];
        }
    }
}

// ---------------------------------------------------------------------------
// merge v2 (R8 version, unchanged).
// ---------------------------------------------------------------------------
__device__ const int g_cnt[8] = {1, 2, 3, 4, 4, 5, 6, 7};
__device__ const int g_s0[8]  = {0, 1, 3, 6, 10, 14, 19, 25};

__global__ __launch_bounds__(256)
void merge_kernel(const u16* __restrict__ pO, const float* __restrict__ pM,
                  const float* __restrict__ pL, float* __restrict__ out)
{
    const int bid = blockIdx.x;
    const int b   = bid >> 8;
    const int rem = bid & 255;
    const int qi  = rem >> 5;
    const int rg  = rem & 31;
    const int c = g_cnt[qi], s0 = g_s0[qi];
    const int tid = threadIdx.x;
    const int r8 = tid >> 5;
    const int dg = tid & 31;

    const int row = rg * 8 + r8;
    const size_t base = ((size_t)b * 32 + s0) * 256 + row;

    float mv[8];
    float M = NEGINF;
    #pragma unroll
    for (int i = 0; i < 8; ++i)
        if (i < c) { mv[i] = pM[base + (size_t)i * 256]; M = fmaxf(M, mv[i]); }
    float L = 0.f, w[8];
    #pragma unroll
    for (int i = 0; i < 8; ++i)
        if (i < c) {
            float e = __expf(mv[i] - M);
            L += pL[base + (size_t)i * 256] * e;
            w[i] = e;
        }
    const float invL = 1.f / L;

    float4 o = {0.f, 0.f, 0.f, 0.f};
    #pragma unroll
    for (int i = 0; i < 8; ++i)
        if (i < c) {
            ushort4 p = *(const ushort4*)(pO + (base + (size_t)i * 256) * 128 + dg * 4);
            float wi = w[i] * invL;
            o.x = fmaf(wi, b2f(p.x), o.x);
            o.y = fmaf(wi, b2f(p.y), o.y);
            o.z = fmaf(wi, b2f(p.z), o.z);
            o.w = fmaf(wi, b2f(p.w), o.w);
        }
    *(float4*)(out + ((size_t)b * Tn + qi * 256 + row) * Kn + dg * 4) = o;
}

// ---------------------------------------------------------------------------
extern "C" void kernel_launch(void* const* d_in, const int* in_sizes, int n_in,
                              void* d_out, int out_size, void* d_ws, size_t ws_size,
                              hipStream_t stream)
{
    const float* x  = (const float*)d_in[0];
    const float* Wq = (const float*)d_in[1];
    const float* Wk = (const float*)d_in[2];
    const float* Wv = (const float*)d_in[3];
    float* out = (float*)d_out;

    u16* ws = (u16*)d_ws;
    const size_t btk = (size_t)Bn * Tn * Kn;       // 2,097,152
    u16* q  = ws;
    u16* k  = ws + btk;
    u16* v  = ws + 2 * btk;
    u16* Wt = ws + 3 * btk;                        // 393216 u16
    u16* pO = ws + 3 * btk + 393216;               // 8,388,608 u16
    float* pM = (float*)(pO + (size_t)8388608);    // 65536 f32
    float* pL = pM + 65536;                        // 65536 f32
    // total ws usage ~30.7 MB

    prep_kernel<<<384, 256, 0, stream>>>(Wq, Wk, Wv, Wt);
    proj6_kernel<<<256, 512, 0, stream>>>(x, Wt, ws);
    attn_kernel<<<dim3(Bn, 32), 512, 0, stream>>>(q, k, v, pO, pM, pL);
    merge_kernel<<<2048, 256, 0, stream>>>(pO, pM, pL, out);
}

// Round 12
// 81.760 us; speedup vs baseline: 1.1331x; 1.1331x over previous
//
#include <hip/hip_runtime.h>
#include <cmath>

#define Bn 8
#define Tn 2048
#define Cn 1024
#define Kn 128

typedef __attribute__((ext_vector_type(8))) short short8;
typedef __attribute__((ext_vector_type(4))) float f32x4;
typedef unsigned short u16;
typedef unsigned int u32;

#define NEGINF (-__builtin_huge_valf())
#define NJOBS 64

__device__ __forceinline__ u16 f2b(float f) {
    u32 u = __float_as_uint(f);
    u32 r = (u + 0x7FFFu + ((u >> 16) & 1u)) >> 16;
    return (u16)r;
}
__device__ __forceinline__ float b2f(u16 v) {
    u32 u = ((u32)v) << 16;
    return __uint_as_float(u);
}
// packed fp32x2 -> bf16x2 (lo -> [15:0], hi -> [31:16]), RNE.
__device__ __forceinline__ u32 cvtpk(float lo, float hi) {
    u32 r;
    asm("v_cvt_pk_bf16_f32 %0, %1, %2" : "=v"(r) : "v"(lo), "v"(hi));
    return r;
}

__device__ __forceinline__ void load_lds16(const u16* g, u16* l) {
    __builtin_amdgcn_global_load_lds(
        (const __attribute__((address_space(1))) u32*)(g),
        (__attribute__((address_space(3))) u32*)(l), 16, 0, 0);
}

// ---------------------------------------------------------------------------
// prep: W [1024 c][128 n] fp32 -> W^T bf16 [3][128 n][1024 c]
// ---------------------------------------------------------------------------
__global__ __launch_bounds__(256)
void prep_kernel(const float* __restrict__ Wq, const float* __restrict__ Wk,
                 const float* __restrict__ Wv, u16* __restrict__ Wt)
{
    int id = blockIdx.x * 256 + threadIdx.x;
    int w   = id >> 15;
    int rem = id & 32767;
    int c   = rem >> 5;
    int n4  = (rem & 31) << 2;
    const float* W = (w == 0) ? Wq : (w == 1) ? Wk : Wv;
    float4 v = *(const float4*)(W + (size_t)c * Kn + n4);
    u16* dst = Wt + (size_t)w * Kn * Cn;
    dst[(size_t)(n4 + 0) * Cn + c] = f2b(v.x);
    dst[(size_t)(n4 + 1) * Cn + c] = f2b(v.y);
    dst[(size_t)(n4 + 2) * Cn + c] = f2b(v.z);
    dst[(size_t)(n4 + 3) * Cn + c] = f2b(v.w);
}

// ---------------------------------------------------------------------------
// proj5 (R8 version, known 38us; structure ceiling for this shape class).
// ---------------------------------------------------------------------------
__global__ __launch_bounds__(256)
void proj5_kernel(const float* __restrict__ x, const u16* __restrict__ Wt,
                  u16* __restrict__ qkv)
{
    const int bid = blockIdx.x;
    const int g8  = bid >> 3, xr = bid & 7;
    const int w   = g8 % 3;
    const int rt  = (g8 / 3) * 8 + xr;           // 0..255
    const u16* wtg = Wt + (size_t)w * Kn * Cn;
    u16* outp = qkv + (size_t)w * Bn * Tn * Kn;
    const int row0 = rt * 64;
    const int tid  = threadIdx.x;
    const int lane = tid & 63;
    const int wid  = tid >> 6;
    const int l15  = lane & 15, lh = lane >> 4;
    const int m0 = (wid >> 1) * 32, n0 = (wid & 1) * 64;

    __shared__ u16 lds[24576];

    auto stageW = [&](int kk, int buf) {
        #pragma unroll
        for (int i = 0; i < 4; ++i) {
            int u = tid + i * 256;
            int n = u >> 3, c8 = u & 7;
            load_lds16(wtg + (size_t)n * Cn + kk + ((c8 ^ (n & 7)) << 3),
                       lds + 8192 + buf * 8192 + u * 8);
        }
    };
    auto loadX = [&](int kk, float4* xr4) {
        #pragma unroll
        for (int i = 0; i < 2; ++i) {
            int u = tid + i * 256;
            int r = u >> 3, c8 = u & 7;
            const float* s = x + (size_t)(row0 + r) * Cn + kk + c8 * 8;
            xr4[2 * i]     = *(const float4*)(s);
            xr4[2 * i + 1] = *(const float4*)(s + 4);
        }
    };
    auto writeX = [&](int buf, const float4* xr4) {
        u16* dst = lds + buf * 4096;
        #pragma unroll
        for (int i = 0; i < 2; ++i) {
            int u = tid + i * 256;
            int r = u >> 3, c8 = u & 7;
            uint4 pk;
            pk.x = cvtpk(xr4[2 * i].x,     xr4[2 * i].y);
            pk.y = cvtpk(xr4[2 * i].z,     xr4[2 * i].w);
            pk.z = cvtpk(xr4[2 * i + 1].x, xr4[2 * i + 1].y);
            pk.w = cvtpk(xr4[2 * i + 1].z, xr4[2 * i + 1].w);
            *(uint4*)(dst + r * 64 + ((c8 ^ (r & 7)) << 3)) = pk;
        }
    };

    f32x4 acc[2][4];
    #pragma unroll
    for (int i = 0; i < 2; ++i)
        #pragma unroll
        for (int j = 0; j < 4; ++j) acc[i][j] = (f32x4){0.f, 0.f, 0.f, 0.f};

    auto compute = [&](int buf) {
        const u16* Xb = lds + buf * 4096;
        const u16* Wb = lds + 8192 + buf * 8192;
        #pragma unroll
        for (int kc = 0; kc < 2; ++kc) {
            short8 af[2], bf[4];
            #pragma unroll
            for (int mg = 0; mg < 2; ++mg) {
                int row = m0 + mg * 16 + l15;
                int ch  = (kc * 4 + lh) ^ (row & 7);
                af[mg] = *(const short8*)(Xb + row * 64 + ch * 8);
            }
            #pragma unroll
            for (int ng = 0; ng < 4; ++ng) {
                int n  = n0 + ng * 16 + l15;
                int ch = (kc * 4 + lh) ^ (n & 7);
                bf[ng] = *(const short8*)(Wb + n * 64 + ch * 8);
            }
            #pragma unroll
            for (int mg = 0; mg < 2; ++mg)
                #pragma unroll
                for (int ng = 0; ng < 4; ++ng)
                    acc[mg][ng] = __builtin_amdgcn_mfma_f32_16x16x32_bf16(
                        af[mg], bf[ng], acc[mg][ng], 0, 0, 0);
        }
    };

    float4 xA[4], xB[4];
    loadX(0, xA);
    stageW(0, 0);
    loadX(64, xB);
    writeX(0, xA);
    asm volatile("s_waitcnt vmcnt(4) lgkmcnt(0)" ::: "memory");
    __builtin_amdgcn_sched_barrier(0);
    __builtin_amdgcn_s_barrier();
    __builtin_amdgcn_sched_barrier(0);

    auto step = [&](int t, float4* XW, float4* XL) {
        const int buf = t & 1;
        if (t + 1 < 16) stageW((t + 1) * 64, buf ^ 1);
        if (t + 2 < 16) loadX((t + 2) * 64, XL);
        compute(buf);
        if (t + 1 < 16) writeX(buf ^ 1, XW);
        if (t < 15) {
            if (t < 14)
                asm volatile("s_waitcnt vmcnt(4) lgkmcnt(0)" ::: "memory");
            else
                asm volatile("s_waitcnt vmcnt(0) lgkmcnt(0)" ::: "memory");
            __builtin_amdgcn_sched_barrier(0);
            __builtin_amdgcn_s_barrier();
            __builtin_amdgcn_sched_barrier(0);
        }
    };

    for (int tt = 0; tt < 8; ++tt) {
        step(2 * tt,     xB, xA);
        step(2 * tt + 1, xA, xB);
    }

    #pragma unroll
    for (int mg = 0; mg < 2; ++mg)
        #pragma unroll
        for (int ng = 0; ng < 4; ++ng)
            #pragma unroll
            for (int r = 0; r < 4; ++r) {
                int m = row0 + m0 + mg * 16 + lh * 4 + r;
                int n = n0 + ng * 16 + l15;
                outp[(size_t)m * Kn + n] = f2b(acc[mg][ng][r]);
            }
}

// ---------------------------------------------------------------------------
// attn v4: R8 wave-level code; s-range of each 256-row q-tile split into 64
// jobs/batch of 2-3 supers -> grid 512 = 2 blocks/CU. K/V staging volume
// UNCHANGED (each super still staged once per q-tile); only q-loads and pO
// partials grow. Batch b pinned to XCD b (bid%8==b), K/V/q L2-resident.
// ---------------------------------------------------------------------------
__device__ const int g_job_qi[NJOBS] = {
    0,0, 1,1,1, 2,2,2,2,2, 3,3,3,3,3,3,3, 4,4,4,4,4,4,4,4,4,
    5,5,5,5,5,5,5,5,5,5, 6,6,6,6,6,6,6,6,6,6,6,6,6,
    7,7,7,7,7,7,7,7,7,7,7,7,7,7,7};
__device__ const int g_sup_b[NJOBS] = {
    0,2, 0,3,6, 0,3,6,8,10, 0,3,6,8,10,12,14, 0,3,6,8,10,12,14,16,18,
    0,3,6,9,12,14,16,18,20,22, 0,3,6,8,10,12,14,16,18,20,22,24,26,
    0,3,6,8,10,12,14,16,18,20,22,24,26,28,30};
__device__ const int g_sup_e[NJOBS] = {
    2,4, 3,6,8, 3,6,8,10,12, 3,6,8,10,12,14,16, 3,6,8,10,12,14,16,18,20,
    3,6,9,12,14,16,18,20,22,24, 3,6,8,10,12,14,16,18,20,22,24,26,28,
    3,6,8,10,12,14,16,18,20,22,24,26,28,30,32};

__global__ __launch_bounds__(512, 2)
void attn_kernel(const u16* __restrict__ qg_, const u16* __restrict__ kg_,
                 const u16* __restrict__ vg_, u16* __restrict__ pO,
                 float* __restrict__ pM, float* __restrict__ pL)
{
    const int b   = blockIdx.x;
    const int job = blockIdx.y;
    const int qi  = g_job_qi[job];
    const int sb  = g_sup_b[job], se = g_sup_e[job];

    const u16* qw = qg_ + (size_t)b * Tn * Kn;
    const u16* kw = kg_ + (size_t)b * Tn * Kn;
    const u16* vw = vg_ + (size_t)b * Tn * Kn;

    const int tid  = threadIdx.x;
    const int lane = tid & 63;
    const int wid  = tid >> 6;
    const int l15  = lane & 15, lh = lane >> 4;

    const int q0 = qi * 256 + wid * 32;
    const int qmax_w = q0 + 31;

    __shared__ u16 lds[32768];

    short8 qf[2][4];
    #pragma unroll
    for (int g = 0; g < 2; ++g)
        #pragma unroll
        for (int kc = 0; kc < 4; ++kc)
            qf[g][kc] = *(const short8*)(qw + (size_t)(q0 + g * 16 + l15) * Kn
                                         + kc * 32 + lh * 8);

    f32x4 acc[8][2];
    #pragma unroll
    for (int dt = 0; dt < 8; ++dt)
        #pragma unroll
        for (int g = 0; g < 2; ++g) acc[dt][g] = (f32x4){0.f, 0.f, 0.f, 0.f};
    float m_g[2] = {NEGINF, NEGINF}, l_g[2] = {0.f, 0.f};

    const float scale = 0.08838834764831843f;

    auto stageK = [&](int sup, int buf) {
        const u16* src = kw + (size_t)sup * 64 * Kn;
        u16* dst = lds + buf * 8192;
        #pragma unroll
        for (int i = 0; i < 2; ++i) {
            int u = wid * 128 + i * 64 + lane;
            int row = u >> 4;
            int c16 = (u & 15) ^ (row & 7);
            load_lds16(src + (size_t)row * Kn + c16 * 8,
                       dst + (size_t)(wid * 128 + i * 64) * 8);
        }
    };
    auto loadV = [&](int sup, uint4* vr) {
        const u16* src = vw + (size_t)sup * 64 * Kn;
        #pragma unroll
        for (int r = 0; r < 2; ++r) {
            int s  = tid & 63;
            int u8 = (tid >> 6) + 8 * r;
            vr[r] = *(const uint4*)(src + (size_t)s * Kn + u8 * 8);
        }
    };
    auto writeV = [&](int buf, const uint4* vr) {
        u16* dst = lds + 16384 + buf * 8192;
        #pragma unroll
        for (int r = 0; r < 2; ++r) {
            int s  = tid & 63;
            int u8 = (tid >> 6) + 8 * r;
            const u16* e = (const u16*)&vr[r];
            #pragma unroll
            for (int j = 0; j < 8; ++j) {
                int d = u8 * 8 + j;
                dst[d * 64 + (((s >> 3) ^ j) << 3) + (s & 7)] = e[j];
            }
        }
    };

    uint4 vreg[2];
    stageK(sb, 0);
    loadV(sb, vreg);
    writeV(0, vreg);

    for (int sup = sb; sup < se; ++sup) {
        const int cur = (sup - sb) & 1;
        __syncthreads();
        const bool have_next = (sup + 1 < se);
        if (have_next) {
            stageK(sup + 1, cur ^ 1);
            loadV(sup + 1, vreg);
        }
        if (sup * 64 <= qmax_w) {
            const u16* Kb = lds + cur * 8192;
            const u16* Vb = lds + 16384 + cur * 8192;
            f32x4 sf[4][2];
            #pragma unroll
            for (int mt = 0; mt < 4; ++mt)
                #pragma unroll
                for (int g = 0; g < 2; ++g) sf[mt][g] = (f32x4){0.f,0.f,0.f,0.f};
            #pragma unroll
            for (int kc = 0; kc < 4; ++kc) {
                short8 a[4];
                #pragma unroll
                for (int mt = 0; mt < 4; ++mt) {
                    int row = mt * 16 + l15;
                    int ch  = (kc * 4 + lh) ^ (row & 7);
                    a[mt] = *(const short8*)(Kb + row * 128 + ch * 8);
                }
                #pragma unroll
                for (int mt = 0; mt < 4; ++mt)
                    #pragma unroll
                    for (int g = 0; g < 2; ++g)
                        sf[mt][g] = __builtin_amdgcn_mfma_f32_16x16x32_bf16(
                            a[mt], qf[g][kc], sf[mt][g], 0, 0, 0);
            }
            const int sbase = sup * 64;
            u32 upk[2][4][2];
            float alpha_g[2];
            #pragma unroll
            for (int g = 0; g < 2; ++g) {
                const int qg = q0 + g * 16 + l15;
                float pv[16];
                float pm = NEGINF;
                #pragma unroll
                for (int mt = 0; mt < 4; ++mt)
                    #pragma unroll
                    for (int r = 0; r < 4; ++r) {
                        int sg = sbase + mt * 16 + lh * 4 + r;
                        float vv = sf[mt][g][r] * scale;
                        vv = (sg > qg) ? NEGINF : vv;
                        pv[mt * 4 + r] = vv;
                        pm = fmaxf(pm, vv);
                    }
                pm = fmaxf(pm, __shfl_xor(pm, 16));
                pm = fmaxf(pm, __shfl_xor(pm, 32));
                float mn  = fmaxf(m_g[g], pm);
                float mns = (mn == NEGINF) ? 0.f : mn;
                float al  = __expf(m_g[g] - mns);
                m_g[g] = mn;
                alpha_g[g] = al;
                float ps = 0.f;
                #pragma unroll
                for (int i = 0; i < 16; ++i) { pv[i] = __expf(pv[i] - mns); ps += pv[i]; }
                ps += __shfl_xor(ps, 16);
                ps += __shfl_xor(ps, 32);
                l_g[g] = l_g[g] * al + ps;
                #pragma unroll
                for (int mt = 0; mt < 4; ++mt)
                    #pragma unroll
                    for (int h = 0; h < 2; ++h)
                        upk[g][mt][h] = (u32)f2b(pv[mt * 4 + 2 * h])
                                      | ((u32)f2b(pv[mt * 4 + 2 * h + 1]) << 16);
            }
            #pragma unroll
            for (int dt = 0; dt < 8; ++dt)
                #pragma unroll
                for (int g = 0; g < 2; ++g)
                    acc[dt][g] *= alpha_g[g];
            #pragma unroll
            for (int ks = 0; ks < 2; ++ks) {
                short8 pf[2];
                #pragma unroll
                for (int g = 0; g < 2; ++g) {
                    union { u32 w[4]; short8 v; } uu;
                    #pragma unroll
                    for (int hp = 0; hp < 4; ++hp) {
                        int srcLane = l15 + 16 * ((lh & 1) * 2 + (hp >> 1));
                        u32 vA = __shfl(upk[g][2 * ks][hp & 1], srcLane, 64);
                        u32 vB = __shfl(upk[g][2 * ks + 1][hp & 1], srcLane, 64);
                        uu.w[hp] = (lh < 2) ? vA : vB;
                    }
                    pf[g] = uu.v;
                }
                #pragma unroll
                for (int dt = 0; dt < 8; ++dt) {
                    int d  = dt * 16 + l15;
                    int ch = (ks * 4 + lh) ^ (d & 7);
                    short8 av = *(const short8*)(Vb + d * 64 + ch * 8);
                    #pragma unroll
                    for (int g = 0; g < 2; ++g)
                        acc[dt][g] = __builtin_amdgcn_mfma_f32_16x16x32_bf16(
                            av, pf[g], acc[dt][g], 0, 0, 0);
                }
            }
        }
        if (have_next) writeV(cur ^ 1, vreg);
    }

    const size_t slotrow = ((size_t)b * NJOBS + job) * 256 + wid * 32;
    #pragma unroll
    for (int g = 0; g < 2; ++g) {
        size_t row = slotrow + g * 16 + l15;
        #pragma unroll
        for (int dt = 0; dt < 8; ++dt) {
            ushort4 o = { f2b(acc[dt][g][0]), f2b(acc[dt][g][1]),
                          f2b(acc[dt][g][2]), f2b(acc[dt][g][3]) };
            *(ushort4*)(pO + row * 128 + dt * 16 + lh * 4) = o;
        }
        if (lh == 0) {
            pM[row] = m_g[g];
            pL[row] = l_g[g];
        }
    }
}

// ---------------------------------------------------------------------------
// merge v4: 8 q-tiles of 256 rows, <=15 chunks each.
// ---------------------------------------------------------------------------
__device__ const int g_cnt[8] = {2, 3, 5, 7, 9, 10, 13, 15};
__device__ const int g_s0[8]  = {0, 2, 5, 10, 17, 26, 36, 49};

__global__ __launch_bounds__(256)
void merge_kernel(const u16* __restrict__ pO, const float* __restrict__ pM,
                  const float* __restrict__ pL, float* __restrict__ out)
{
    const int bid = blockIdx.x;       // 0..2047
    const int b   = bid >> 8;
    const int rem = bid & 255;
    const int qi  = rem >> 5;         // 0..7
    const int rg  = rem & 31;         // rowgroup (8 rows)
    const int c = g_cnt[qi], s0 = g_s0[qi];
    const int tid = threadIdx.x;
    const int r8 = tid >> 5;          // 0..7
    const int dg = tid & 31;          // 0..31 -> d = dg*4

    const int row = rg * 8 + r8;
    const size_t base = ((size_t)b * NJOBS + s0) * 256 + row;

    float mv[15];
    float M = NEGINF;
    #pragma unroll
    for (int i = 0; i < 15; ++i)
        if (i < c) { mv[i] = pM[base + (size_t)i * 256]; M = fmaxf(M, mv[i]); }
    float L = 0.f, w[15];
    #pragma unroll
    for (int i = 0; i < 15; ++i)
        if (i < c) {
            float e = __expf(mv[i] - M);
            L += pL[base + (size_t)i * 256] * e;
            w[i] = e;
        }
    const float invL = 1.f / L;

    float4 o = {0.f, 0.f, 0.f, 0.f};
    #pragma unroll
    for (int i = 0; i < 15; ++i)
        if (i < c) {
            ushort4 p = *(const ushort4*)(pO + (base + (size_t)i * 256) * 128 + dg * 4);
            float wi = w[i] * invL;
            o.x = fmaf(wi, b2f(p.x), o.x);
            o.y = fmaf(wi, b2f(p.y), o.y);
            o.z = fmaf(wi, b2f(p.z), o.z);
            o.w = fmaf(wi, b2f(p.w), o.w);
        }
    *(float4*)(out + ((size_t)b * Tn + qi * 256 + row) * Kn + dg * 4) = o;
}

// ---------------------------------------------------------------------------
extern "C" void kernel_launch(void* const* d_in, const int* in_sizes, int n_in,
                              void* d_out, int out_size, void* d_ws, size_t ws_size,
                              hipStream_t stream)
{
    const float* x  = (const float*)d_in[0];
    const float* Wq = (const float*)d_in[1];
    const float* Wk = (const float*)d_in[2];
    const float* Wv = (const float*)d_in[3];
    float* out = (float*)d_out;

    u16* ws = (u16*)d_ws;
    const size_t btk = (size_t)Bn * Tn * Kn;           // 2,097,152
    u16* q  = ws;
    u16* k  = ws + btk;
    u16* v  = ws + 2 * btk;
    u16* Wt = ws + 3 * btk;                            // 393216 u16
    u16* pO = ws + 3 * btk + 393216;                   // 8*64*256*128 = 16,777,216 u16
    float* pM = (float*)(pO + (size_t)16777216);       // 131072 f32
    float* pL = pM + 131072;                           // 131072 f32
    // total ws ~48 MB

    prep_kernel<<<384, 256, 0, stream>>>(Wq, Wk, Wv, Wt);
    proj5_kernel<<<768, 256, 0, stream>>>(x, Wt, ws);
    attn_kernel<<<dim3(Bn, NJOBS), 512, 0, stream>>>(q, k, v, pO, pM, pL);
    merge_kernel<<<2048, 256, 0, stream>>>(pO, pM, pL, out);
}

// Round 13
// 67.644 us; speedup vs baseline: 1.3695x; 1.2087x over previous
//
#include <hip/hip_runtime.h>
#include <cmath>

#define Bn 8
#define Tn 2048
#define Cn 1024
#define Kn 128

typedef __attribute__((ext_vector_type(8))) short short8;
typedef __attribute__((ext_vector_type(4))) float f32x4;
typedef unsigned short u16;
typedef unsigned int u32;

#define NEGINF (-__builtin_huge_valf())

__device__ __forceinline__ u16 f2b(float f) {
    u32 u = __float_as_uint(f);
    u32 r = (u + 0x7FFFu + ((u >> 16) & 1u)) >> 16;
    return (u16)r;
}
__device__ __forceinline__ float b2f(u16 v) {
    u32 u = ((u32)v) << 16;
    return __uint_as_float(u);
}
// packed fp32x2 -> bf16x2 (lo -> [15:0], hi -> [31:16]), RNE.
__device__ __forceinline__ u32 cvtpk(float lo, float hi) {
    u32 r;
    asm("v_cvt_pk_bf16_f32 %0, %1, %2" : "=v"(r) : "v"(lo), "v"(hi));
    return r;
}

__device__ __forceinline__ void load_lds16(const u16* g, u16* l) {
    __builtin_amdgcn_global_load_lds(
        (const __attribute__((address_space(1))) u32*)(g),
        (__attribute__((address_space(3))) u32*)(l), 16, 0, 0);
}

// ---------------------------------------------------------------------------
// prep: W [1024 c][128 n] fp32 -> W^T bf16 [3][128 n][1024 c]
// ---------------------------------------------------------------------------
__global__ __launch_bounds__(256)
void prep_kernel(const float* __restrict__ Wq, const float* __restrict__ Wk,
                 const float* __restrict__ Wv, u16* __restrict__ Wt)
{
    int id = blockIdx.x * 256 + threadIdx.x;
    int w   = id >> 15;
    int rem = id & 32767;
    int c   = rem >> 5;
    int n4  = (rem & 31) << 2;
    const float* W = (w == 0) ? Wq : (w == 1) ? Wk : Wv;
    float4 v = *(const float4*)(W + (size_t)c * Kn + n4);
    u16* dst = Wt + (size_t)w * Kn * Cn;
    dst[(size_t)(n4 + 0) * Cn + c] = f2b(v.x);
    dst[(size_t)(n4 + 1) * Cn + c] = f2b(v.y);
    dst[(size_t)(n4 + 2) * Cn + c] = f2b(v.z);
    dst[(size_t)(n4 + 3) * Cn + c] = f2b(v.w);
}

// ---------------------------------------------------------------------------
// proj5 (R8 version, known-good 38us; structure ceiling for this shape).
// ---------------------------------------------------------------------------
__global__ __launch_bounds__(256)
void proj5_kernel(const float* __restrict__ x, const u16* __restrict__ Wt,
                  u16* __restrict__ qkv)
{
    const int bid = blockIdx.x;
    const int g8  = bid >> 3, xr = bid & 7;
    const int w   = g8 % 3;
    const int rt  = (g8 / 3) * 8 + xr;           // 0..255
    const u16* wtg = Wt + (size_t)w * Kn * Cn;
    u16* outp = qkv + (size_t)w * Bn * Tn * Kn;
    const int row0 = rt * 64;
    const int tid  = threadIdx.x;
    const int lane = tid & 63;
    const int wid  = tid >> 6;
    const int l15  = lane & 15, lh = lane >> 4;
    const int m0 = (wid >> 1) * 32, n0 = (wid & 1) * 64;

    __shared__ u16 lds[24576];

    auto stageW = [&](int kk, int buf) {
        #pragma unroll
        for (int i = 0; i < 4; ++i) {
            int u = tid + i * 256;
            int n = u >> 3, c8 = u & 7;
            load_lds16(wtg + (size_t)n * Cn + kk + ((c8 ^ (n & 7)) << 3),
                       lds + 8192 + buf * 8192 + u * 8);
        }
    };
    auto loadX = [&](int kk, float4* xr4) {
        #pragma unroll
        for (int i = 0; i < 2; ++i) {
            int u = tid + i * 256;
            int r = u >> 3, c8 = u & 7;
            const float* s = x + (size_t)(row0 + r) * Cn + kk + c8 * 8;
            xr4[2 * i]     = *(const float4*)(s);
            xr4[2 * i + 1] = *(const float4*)(s + 4);
        }
    };
    auto writeX = [&](int buf, const float4* xr4) {
        u16* dst = lds + buf * 4096;
        #pragma unroll
        for (int i = 0; i < 2; ++i) {
            int u = tid + i * 256;
            int r = u >> 3, c8 = u & 7;
            uint4 pk;
            pk.x = cvtpk(xr4[2 * i].x,     xr4[2 * i].y);
            pk.y = cvtpk(xr4[2 * i].z,     xr4[2 * i].w);
            pk.z = cvtpk(xr4[2 * i + 1].x, xr4[2 * i + 1].y);
            pk.w = cvtpk(xr4[2 * i + 1].z, xr4[2 * i + 1].w);
            *(uint4*)(dst + r * 64 + ((c8 ^ (r & 7)) << 3)) = pk;
        }
    };

    f32x4 acc[2][4];
    #pragma unroll
    for (int i = 0; i < 2; ++i)
        #pragma unroll
        for (int j = 0; j < 4; ++j) acc[i][j] = (f32x4){0.f, 0.f, 0.f, 0.f};

    auto compute = [&](int buf) {
        const u16* Xb = lds + buf * 4096;
        const u16* Wb = lds + 8192 + buf * 8192;
        #pragma unroll
        for (int kc = 0; kc < 2; ++kc) {
            short8 af[2], bf[4];
            #pragma unroll
            for (int mg = 0; mg < 2; ++mg) {
                int row = m0 + mg * 16 + l15;
                int ch  = (kc * 4 + lh) ^ (row & 7);
                af[mg] = *(const short8*)(Xb + row * 64 + ch * 8);
            }
            #pragma unroll
            for (int ng = 0; ng < 4; ++ng) {
                int n  = n0 + ng * 16 + l15;
                int ch = (kc * 4 + lh) ^ (n & 7);
                bf[ng] = *(const short8*)(Wb + n * 64 + ch * 8);
            }
            #pragma unroll
            for (int mg = 0; mg < 2; ++mg)
                #pragma unroll
                for (int ng = 0; ng < 4; ++ng)
                    acc[mg][ng] = __builtin_amdgcn_mfma_f32_16x16x32_bf16(
                        af[mg], bf[ng], acc[mg][ng], 0, 0, 0);
        }
    };

    float4 xA[4], xB[4];
    loadX(0, xA);
    stageW(0, 0);
    loadX(64, xB);
    writeX(0, xA);
    asm volatile("s_waitcnt vmcnt(4) lgkmcnt(0)" ::: "memory");
    __builtin_amdgcn_sched_barrier(0);
    __builtin_amdgcn_s_barrier();
    __builtin_amdgcn_sched_barrier(0);

    auto step = [&](int t, float4* XW, float4* XL) {
        const int buf = t & 1;
        if (t + 1 < 16) stageW((t + 1) * 64, buf ^ 1);
        if (t + 2 < 16) loadX((t + 2) * 64, XL);
        compute(buf);
        if (t + 1 < 16) writeX(buf ^ 1, XW);
        if (t < 15) {
            if (t < 14)
                asm volatile("s_waitcnt vmcnt(4) lgkmcnt(0)" ::: "memory");
            else
                asm volatile("s_waitcnt vmcnt(0) lgkmcnt(0)" ::: "memory");
            __builtin_amdgcn_sched_barrier(0);
            __builtin_amdgcn_s_barrier();
            __builtin_amdgcn_sched_barrier(0);
        }
    };

    for (int tt = 0; tt < 8; ++tt) {
        step(2 * tt,     xB, xA);
        step(2 * tt + 1, xA, xB);
    }

    #pragma unroll
    for (int mg = 0; mg < 2; ++mg)
        #pragma unroll
        for (int ng = 0; ng < 4; ++ng)
            #pragma unroll
            for (int r = 0; r < 4; ++r) {
                int m = row0 + m0 + mg * 16 + lh * 4 + r;
                int n = n0 + ng * 16 + l15;
                outp[(size_t)m * Kn + n] = f2b(acc[mg][ng][r]);
            }
}

// ---------------------------------------------------------------------------
// attn: causal flash, split-s equal-work blocks (R8 structure: 256-row
// q-tiles, 8 warps x 32 q-rows, 32 jobs/batch). Single change vs R8:
// T13 defer-max -- skip O-rescale when __all(pmax - m <= 8) (wave-uniform).
// ---------------------------------------------------------------------------
__device__ const int g_job_qi[32] = {0, 1,1, 2,2,2, 3,3,3,3, 4,4,4,4,
                                     5,5,5,5,5, 6,6,6,6,6,6, 7,7,7,7,7,7,7};
__device__ const int g_sup_b[32] = {0, 0,4, 0,4,8, 0,4,8,12, 0,5,10,15,
                                    0,4,9,14,19, 0,4,9,14,18,23, 0,4,9,13,18,22,27};
__device__ const int g_sup_e[32] = {4, 4,8, 4,8,12, 4,8,12,16, 5,10,15,20,
                                    4,9,14,19,24, 4,9,14,18,23,28, 4,9,13,18,22,27,32};

__global__ __launch_bounds__(512, 2)
void attn_kernel(const u16* __restrict__ qg_, const u16* __restrict__ kg_,
                 const u16* __restrict__ vg_, u16* __restrict__ pO,
                 float* __restrict__ pM, float* __restrict__ pL)
{
    const int b   = blockIdx.x;
    const int job = blockIdx.y;
    const int qi  = g_job_qi[job];
    const int sb  = g_sup_b[job], se = g_sup_e[job];

    const u16* qw = qg_ + (size_t)b * Tn * Kn;
    const u16* kw = kg_ + (size_t)b * Tn * Kn;
    const u16* vw = vg_ + (size_t)b * Tn * Kn;

    const int tid  = threadIdx.x;
    const int lane = tid & 63;
    const int wid  = tid >> 6;
    const int l15  = lane & 15, lh = lane >> 4;

    const int q0 = qi * 256 + wid * 32;
    const int qmax_w = q0 + 31;

    __shared__ u16 lds[32768];

    short8 qf[2][4];
    #pragma unroll
    for (int g = 0; g < 2; ++g)
        #pragma unroll
        for (int kc = 0; kc < 4; ++kc)
            qf[g][kc] = *(const short8*)(qw + (size_t)(q0 + g * 16 + l15) * Kn
                                         + kc * 32 + lh * 8);

    f32x4 acc[8][2];
    #pragma unroll
    for (int dt = 0; dt < 8; ++dt)
        #pragma unroll
        for (int g = 0; g < 2; ++g) acc[dt][g] = (f32x4){0.f, 0.f, 0.f, 0.f};
    float m_g[2] = {NEGINF, NEGINF}, l_g[2] = {0.f, 0.f};

    const float scale = 0.08838834764831843f;

    auto stageK = [&](int sup, int buf) {
        const u16* src = kw + (size_t)sup * 64 * Kn;
        u16* dst = lds + buf * 8192;
        #pragma unroll
        for (int i = 0; i < 2; ++i) {
            int u = wid * 128 + i * 64 + lane;
            int row = u >> 4;
            int c16 = (u & 15) ^ (row & 7);
            load_lds16(src + (size_t)row * Kn + c16 * 8,
                       dst + (size_t)(wid * 128 + i * 64) * 8);
        }
    };
    auto loadV = [&](int sup, uint4* vr) {
        const u16* src = vw + (size_t)sup * 64 * Kn;
        #pragma unroll
        for (int r = 0; r < 2; ++r) {
            int s  = tid & 63;
            int u8 = (tid >> 6) + 8 * r;
            vr[r] = *(const uint4*)(src + (size_t)s * Kn + u8 * 8);
        }
    };
    auto writeV = [&](int buf, const uint4* vr) {
        u16* dst = lds + 16384 + buf * 8192;
        #pragma unroll
        for (int r = 0; r < 2; ++r) {
            int s  = tid & 63;
            int u8 = (tid >> 6) + 8 * r;
            const u16* e = (const u16*)&vr[r];
            #pragma unroll
            for (int j = 0; j < 8; ++j) {
                int d = u8 * 8 + j;
                dst[d * 64 + (((s >> 3) ^ j) << 3) + (s & 7)] = e[j];
            }
        }
    };

    uint4 vreg[2];
    stageK(sb, 0);
    loadV(sb, vreg);
    writeV(0, vreg);

    for (int sup = sb; sup < se; ++sup) {
        const int cur = (sup - sb) & 1;
        __syncthreads();
        const bool have_next = (sup + 1 < se);
        if (have_next) {
            stageK(sup + 1, cur ^ 1);
            loadV(sup + 1, vreg);
        }
        if (sup * 64 <= qmax_w) {
            const u16* Kb = lds + cur * 8192;
            const u16* Vb = lds + 16384 + cur * 8192;
            f32x4 sf[4][2];
            #pragma unroll
            for (int mt = 0; mt < 4; ++mt)
                #pragma unroll
                for (int g = 0; g < 2; ++g) sf[mt][g] = (f32x4){0.f,0.f,0.f,0.f};
            #pragma unroll
            for (int kc = 0; kc < 4; ++kc) {
                short8 a[4];
                #pragma unroll
                for (int mt = 0; mt < 4; ++mt) {
                    int row = mt * 16 + l15;
                    int ch  = (kc * 4 + lh) ^ (row & 7);
                    a[mt] = *(const short8*)(Kb + row * 128 + ch * 8);
                }
                #pragma unroll
                for (int mt = 0; mt < 4; ++mt)
                    #pragma unroll
                    for (int g = 0; g < 2; ++g)
                        sf[mt][g] = __builtin_amdgcn_mfma_f32_16x16x32_bf16(
                            a[mt], qf[g][kc], sf[mt][g], 0, 0, 0);
            }
            const int sbase = sup * 64;

            // ---- masked scores + per-row max ----
            float pvv[2][16];
            float pmax2[2];
            #pragma unroll
            for (int g = 0; g < 2; ++g) {
                const int qg = q0 + g * 16 + l15;
                float pm = NEGINF;
                #pragma unroll
                for (int mt = 0; mt < 4; ++mt)
                    #pragma unroll
                    for (int r = 0; r < 4; ++r) {
                        int sg = sbase + mt * 16 + lh * 4 + r;
                        float vv = sf[mt][g][r] * scale;
                        vv = (sg > qg) ? NEGINF : vv;
                        pvv[g][mt * 4 + r] = vv;
                        pm = fmaxf(pm, vv);
                    }
                pm = fmaxf(pm, __shfl_xor(pm, 16));
                pm = fmaxf(pm, __shfl_xor(pm, 32));
                pmax2[g] = pm;
            }

            // ---- T13 defer-max: wave-uniform skip of the rescale ----
            // (NaN/inf on first tile compares false -> normal path.)
            const bool defer = __all((pmax2[0] - m_g[0] <= 8.f) &&
                                     (pmax2[1] - m_g[1] <= 8.f));

            u32 upk[2][4][2];
            float alpha_g[2];
            #pragma unroll
            for (int g = 0; g < 2; ++g) {
                float mns;
                if (defer) {
                    mns = m_g[g];              // finite (guaranteed by defer)
                    alpha_g[g] = 1.f;
                } else {
                    float mn = fmaxf(m_g[g], pmax2[g]);
                    mns = (mn == NEGINF) ? 0.f : mn;
                    alpha_g[g] = __expf(m_g[g] - mns);
                    m_g[g] = mn;
                }
                float ps = 0.f;
                #pragma unroll
                for (int i = 0; i < 16; ++i) {
                    pvv[g][i] = __expf(pvv[g][i] - mns);
                    ps += pvv[g][i];
                }
                ps += __shfl_xor(ps, 16);
                ps += __shfl_xor(ps, 32);
                l_g[g] = l_g[g] * alpha_g[g] + ps;
                #pragma unroll
                for (int mt = 0; mt < 4; ++mt)
                    #pragma unroll
                    for (int h = 0; h < 2; ++h)
                        upk[g][mt][h] = (u32)f2b(pvv[g][mt * 4 + 2 * h])
                                      | ((u32)f2b(pvv[g][mt * 4 + 2 * h + 1]) << 16);
            }
            if (!defer) {
                #pragma unroll
                for (int dt = 0; dt < 8; ++dt)
                    #pragma unroll
                    for (int g = 0; g < 2; ++g)
                        acc[dt][g] *= alpha_g[g];
            }
            #pragma unroll
            for (int ks = 0; ks < 2; ++ks) {
                short8 pf[2];
                #pragma unroll
                for (int g = 0; g < 2; ++g) {
                    union { u32 w[4]; short8 v; } uu;
                    #pragma unroll
                    for (int hp = 0; hp < 4; ++hp) {
                        int srcLane = l15 + 16 * ((lh & 1) * 2 + (hp >> 1));
                        u32 vA = __shfl(upk[g][2 * ks][hp & 1], srcLane, 64);
                        u32 vB = __shfl(upk[g][2 * ks + 1][hp & 1], srcLane, 64);
                        uu.w[hp] = (lh < 2) ? vA : vB;
                    }
                    pf[g] = uu.v;
                }
                #pragma unroll
                for (int dt = 0; dt < 8; ++dt) {
                    int d  = dt * 16 + l15;
                    int ch = (ks * 4 + lh) ^ (d & 7);
                    short8 av = *(const short8*)(Vb + d * 64 + ch * 8);
                    #pragma unroll
                    for (int g = 0; g < 2; ++g)
                        acc[dt][g] = __builtin_amdgcn_mfma_f32_16x16x32_bf16(
                            av, pf[g], acc[dt][g], 0, 0, 0);
                }
            }
        }
        if (have_next) writeV(cur ^ 1, vreg);
    }

    const size_t slotrow = ((size_t)b * 32 + job) * 256 + wid * 32;
    #pragma unroll
    for (int g = 0; g < 2; ++g) {
        size_t row = slotrow + g * 16 + l15;
        #pragma unroll
        for (int dt = 0; dt < 8; ++dt) {
            ushort4 o = { f2b(acc[dt][g][0]), f2b(acc[dt][g][1]),
                          f2b(acc[dt][g][2]), f2b(acc[dt][g][3]) };
            *(ushort4*)(pO + row * 128 + dt * 16 + lh * 4) = o;
        }
        if (lh == 0) {
            pM[row] = m_g[g];
            pL[row] = l_g[g];
        }
    }
}

// ---------------------------------------------------------------------------
// merge v2 (R8 version, unchanged).
// ---------------------------------------------------------------------------
__device__ const int g_cnt[8] = {1, 2, 3, 4, 4, 5, 6, 7};
__device__ const int g_s0[8]  = {0, 1, 3, 6, 10, 14, 19, 25};

__global__ __launch_bounds__(256)
void merge_kernel(const u16* __restrict__ pO, const float* __restrict__ pM,
                  const float* __restrict__ pL, float* __restrict__ out)
{
    const int bid = blockIdx.x;
    const int b   = bid >> 8;
    const int rem = bid & 255;
    const int qi  = rem >> 5;
    const int rg  = rem & 31;
    const int c = g_cnt[qi], s0 = g_s0[qi];
    const int tid = threadIdx.x;
    const int r8 = tid >> 5;
    const int dg = tid & 31;

    const int row = rg * 8 + r8;
    const size_t base = ((size_t)b * 32 + s0) * 256 + row;

    float mv[8];
    float M = NEGINF;
    #pragma unroll
    for (int i = 0; i < 8; ++i)
        if (i < c) { mv[i] = pM[base + (size_t)i * 256]; M = fmaxf(M, mv[i]); }
    float L = 0.f, w[8];
    #pragma unroll
    for (int i = 0; i < 8; ++i)
        if (i < c) {
            float e = __expf(mv[i] - M);
            L += pL[base + (size_t)i * 256] * e;
            w[i] = e;
        }
    const float invL = 1.f / L;

    float4 o = {0.f, 0.f, 0.f, 0.f};
    #pragma unroll
    for (int i = 0; i < 8; ++i)
        if (i < c) {
            ushort4 p = *(const ushort4*)(pO + (base + (size_t)i * 256) * 128 + dg * 4);
            float wi = w[i] * invL;
            o.x = fmaf(wi, b2f(p.x), o.x);
            o.y = fmaf(wi, b2f(p.y), o.y);
            o.z = fmaf(wi, b2f(p.z), o.z);
            o.w = fmaf(wi, b2f(p.w), o.w);
        }
    *(float4*)(out + ((size_t)b * Tn + qi * 256 + row) * Kn + dg * 4) = o;
}

// ---------------------------------------------------------------------------
extern "C" void kernel_launch(void* const* d_in, const int* in_sizes, int n_in,
                              void* d_out, int out_size, void* d_ws, size_t ws_size,
                              hipStream_t stream)
{
    const float* x  = (const float*)d_in[0];
    const float* Wq = (const float*)d_in[1];
    const float* Wk = (const float*)d_in[2];
    const float* Wv = (const float*)d_in[3];
    float* out = (float*)d_out;

    u16* ws = (u16*)d_ws;
    const size_t btk = (size_t)Bn * Tn * Kn;       // 2,097,152
    u16* q  = ws;
    u16* k  = ws + btk;
    u16* v  = ws + 2 * btk;
    u16* Wt = ws + 3 * btk;                        // 393216 u16
    u16* pO = ws + 3 * btk + 393216;               // 8,388,608 u16
    float* pM = (float*)(pO + (size_t)8388608);    // 65536 f32
    float* pL = pM + 65536;                        // 65536 f32
    // total ws usage ~30.7 MB

    prep_kernel<<<384, 256, 0, stream>>>(Wq, Wk, Wv, Wt);
    proj5_kernel<<<768, 256, 0, stream>>>(x, Wt, ws);
    attn_kernel<<<dim3(Bn, 32), 512, 0, stream>>>(q, k, v, pO, pM, pL);
    merge_kernel<<<2048, 256, 0, stream>>>(pO, pM, pL, out);
}